// Round 6
// baseline (237.041 us; speedup 1.0000x reference)
//
#include <hip/hip_runtime.h>

// out[r, i] = sum_{k=0..4} W[i,k] * x[r, i+k-2] + b[i], zero-padded at edges.
// B=8192 rows, C=4096 channels, K=5, fp32.
//
// R1: per-(row,channel) W loads -> L1/TA line-request bound.
// R2: thread owns 4 channels, W+bias in regs, loops rows. 91 us/dispatch.
// R3: 4096 blocks (16/CU backfill): occupancy 56->67%, 83 us. nt stores FAILED.
// R4: wave-edge halo via __shfl: ~76 us.
// R5/R6: register software pipelines FAILED (compiler sinks loads or spills
//   arrays to scratch). Register pipelines are unholdable at this occupancy.
// R7: global_load_lds staging (no dest VGPR -> nothing to sink/spill), 4-row
//   tile, stage->BARRIER->compute: ~67 us. Gap to 43 us copy-floor remains:
//   the vmcnt(0) drain sits BEFORE compute, so waves never have loads in
//   flight while computing; overlap was cross-block only (phase-synced).
// R8 (this): m97/T3 2-phase double buffer. Order per tile: STAGE(t+1) ->
//   COMPUTE(t) -> drain -> barrier. Next tile's 2KB/wave stays in flight
//   through compute; wave re-issues immediately after barrier. LDS 2 bufs x
//   2 rows x 4KB = 16.6KB -> still 8 blocks/CU (full 32-wave occupancy).
//   Halo float2 -> VGPR at stage time, ds_write after compute (compiler's
//   own vmcnt dep-wait = our drain point, wave0 only).
// Hooks: LDS ~16640B, VGPR ~48, WRITE=131072KB. If >=65 us with clean
//   counters -> DRAM r/w-mix wall -> roofline.

#define B_ROWS 8192
#define C_CH   4096
#define TROWS  2            // rows per tile
#define NT     4            // tiles per block -> 8 rows/block
#define NCHK   256          // float4 chunks per block slice (1024 channels)

typedef unsigned int u32;

__global__ __launch_bounds__(256, 8) void grouped_linear_kernel(
    const float* __restrict__ x, const float* __restrict__ W,
    const float* __restrict__ bias, float* __restrict__ out)
{
    __shared__ __align__(16) float lds_rows[2][TROWS][1024];
    __shared__ __align__(16) float lds_hL[2][TROWS][4];  // [2],[3] = x[row][blk-2..blk-1]
    __shared__ __align__(16) float lds_hR[2][TROWS][4];  // [0],[1] = x[row][blk+1024..1025]

    const int tid   = threadIdx.x;
    const int bx    = blockIdx.x;                // 0..3
    const int r0    = blockIdx.y * (TROWS * NT);
    const int chunk = bx * NCHK + tid;           // global float4 index in row
    const int c     = chunk << 2;

    // --- loop-invariant: W rows c..c+3 (20 contiguous floats) + bias ---
    const float4* W4 = (const float4*)(W + (size_t)c * 5);
    const float4 w0 = W4[0];  // W[c][0..3]
    const float4 w1 = W4[1];  // W[c][4], W[c+1][0..2]
    const float4 w2 = W4[2];  // W[c+1][3..4], W[c+2][0..1]
    const float4 w3 = W4[3];  // W[c+2][2..4], W[c+3][0]
    const float4 w4 = W4[4];  // W[c+3][1..4]
    const float4 bv = ((const float4*)bias)[chunk];

    const int wave = tid >> 6;
    const float* gbase = x + (size_t)r0 * C_CH + bx * 1024 + tid * 4;
    float4* obase = (float4*)(out + (size_t)r0 * C_CH) + chunk;

    // halo loader (threads 0..2*TROWS-1): hr = row in tile, hside = L/R
    const int  hr     = tid >> 1;
    const int  hside  = tid & 1;
    const int  hgc    = bx * 1024 + (hside ? 1024 : -2);
    const bool hvalid = (tid < 2 * TROWS) && (hgc >= 0) && (hgc + 1 < C_CH);
    const float* hbase = x + (size_t)(r0 + hr) * C_CH + hgc;  // deref only if hvalid

#define STAGE(buf_, t_) {                                                      \
    const float* g_ = gbase + (size_t)(t_) * TROWS * C_CH;                     \
    _Pragma("unroll")                                                          \
    for (int r_ = 0; r_ < TROWS; ++r_)                                         \
        __builtin_amdgcn_global_load_lds(                                      \
            (const __attribute__((address_space(1))) u32*)(g_ + r_ * C_CH),    \
            (__attribute__((address_space(3))) u32*)&lds_rows[buf_][r_][wave * 256], \
            16, 0, 0);                                                         \
  }

#define HLOAD(t_) {                                                            \
    hv = make_float2(0.f, 0.f);                                                \
    if (hvalid) hv = *(const float2*)(hbase + (size_t)(t_) * TROWS * C_CH);    \
  }

#define HWRITE(buf_) {                                                         \
    if (tid < 2 * TROWS) {                                                     \
        float* d_ = hside ? &lds_hR[buf_][hr][0] : &lds_hL[buf_][hr][2];       \
        *(float2*)d_ = hv;                                                     \
    }                                                                          \
  }

#define COMPUTE(buf_, t_) {                                                    \
    _Pragma("unroll")                                                          \
    for (int r_ = 0; r_ < TROWS; ++r_) {                                       \
        const float* rowp = lds_rows[buf_][r_];                                \
        const int f = tid * 4;                                                 \
        const float4 pm = (tid > 0) ? *(const float4*)(rowp + f - 4)           \
                                    : *(const float4*)lds_hL[buf_][r_];        \
        const float4 pc = *(const float4*)(rowp + f);                          \
        const float4 pp = (tid < NCHK - 1) ? *(const float4*)(rowp + f + 4)    \
                                           : *(const float4*)lds_hR[buf_][r_]; \
        const float win0 = pm.z, win1 = pm.w;                                  \
        const float win2 = pc.x, win3 = pc.y, win4 = pc.z, win5 = pc.w;        \
        const float win6 = pp.x, win7 = pp.y;                                  \
        float4 o;                                                              \
        o.x = fmaf(w0.x, win0, fmaf(w0.y, win1, fmaf(w0.z, win2, fmaf(w0.w, win3, fmaf(w1.x, win4, bv.x))))); \
        o.y = fmaf(w1.y, win1, fmaf(w1.z, win2, fmaf(w1.w, win3, fmaf(w2.x, win4, fmaf(w2.y, win5, bv.y))))); \
        o.z = fmaf(w2.z, win2, fmaf(w2.w, win3, fmaf(w3.x, win4, fmaf(w3.y, win5, fmaf(w3.z, win6, bv.z))))); \
        o.w = fmaf(w3.w, win3, fmaf(w4.x, win4, fmaf(w4.y, win5, fmaf(w4.z, win6, fmaf(w4.w, win7, bv.w))))); \
        obase[((t_) * TROWS + r_) * (C_CH / 4)] = o;                           \
    }                                                                          \
  }

    float2 hv;

    // ---- prologue: stage tile 0, land its halo, one barrier ----
    STAGE(0, 0);
    HLOAD(0);
    HWRITE(0);        // compiler inserts the vmcnt wait for hv here (wave0)
    __syncthreads();  // drains vmcnt(0)+lgkmcnt(0): tile 0 fully resident

    // ---- 2-phase main loop: stage t+1 in flight DURING compute t ----
    #pragma unroll
    for (int t = 0; t < NT; ++t) {
        const int cur = t & 1;
        if (t + 1 < NT) {
            STAGE(cur ^ 1, t + 1);   // issue next tile first (fire-and-forget)
            HLOAD(t + 1);
        }
        COMPUTE(cur, t);             // ds_read + FMA + store, loads in flight
        if (t + 1 < NT) {
            HWRITE(cur ^ 1);         // hv dep -> vmcnt drain lands HERE (post-compute)
            __syncthreads();         // tile t+1 resident; buf cur free for t+2
        }
    }
}

extern "C" void kernel_launch(void* const* d_in, const int* in_sizes, int n_in,
                              void* d_out, int out_size, void* d_ws, size_t ws_size,
                              hipStream_t stream) {
    const float* x    = (const float*)d_in[0];
    const float* W    = (const float*)d_in[1];
    const float* bias = (const float*)d_in[2];
    float* out = (float*)d_out;

    dim3 grid(C_CH / 1024, B_ROWS / (TROWS * NT));   // (4, 1024) = 4096 blocks
    dim3 block(256);
    grouped_linear_kernel<<<grid, block, 0, stream>>>(x, W, bias, out);
}